// Round 1
// baseline (512.649 us; speedup 1.0000x reference)
//
#include <hip/hip_runtime.h>

// VQEmbedding: x [N=32768, D=256] fp32, embedding [M=1024, D=256] fp32.
// Outputs (flat fp32): quantized [N*D], loss [1], indices [N] (as float), perplexity [1].
// dist argmin uses ||e||^2 - 2 x.e (||x||^2 constant per row); loss adds ||x||^2 back.

constexpr int D = 256;
constexpr int M = 1024;
constexpr int ROWS = 64;   // rows per block in main kernel

// ---------------- kernel A: ||e||^2 per codebook row ----------------
__global__ void enorm_kernel(const float* __restrict__ e, float* __restrict__ enorm) {
    int m = blockIdx.x;
    int l = threadIdx.x;  // 64 threads: one float4 each covers D=256 exactly
    const float4 v = *reinterpret_cast<const float4*>(e + m * D + l * 4);
    float s = fmaf(v.x, v.x, fmaf(v.y, v.y, fmaf(v.z, v.z, v.w * v.w)));
#pragma unroll
    for (int o = 32; o > 0; o >>= 1) s += __shfl_down(s, o, 64);
    if (l == 0) enorm[m] = s;
}

// ---------------- kernel B: distances + argmin + gather + loss/count ----------------
// ws layout (floats): [0] loss_sum, [1 .. 1+M) counts, [1+M .. 1+2M) enorm
__global__ __launch_bounds__(256, 2) void vq_main_kernel(
    const float* __restrict__ x, const float* __restrict__ e,
    float* __restrict__ outQ, float* __restrict__ outIdx,
    float* __restrict__ ws) {
    __shared__ float4 xs[ROWS][64];   // 64 KB, column XOR-swizzled by (row&7)
    __shared__ float cval[4][ROWS];
    __shared__ int   cidx[4][ROWS];
    __shared__ int   fidx[ROWS];

    const int tid  = threadIdx.x;
    const int row0 = blockIdx.x * ROWS;

    // stage x tile: coalesced global float4 reads -> swizzled LDS
#pragma unroll
    for (int it = 0; it < 16; ++it) {
        int f  = it * 256 + tid;       // 4096 float4s per tile
        int rr = f >> 6, c4 = f & 63;
        float4 v = *reinterpret_cast<const float4*>(x + (row0 + rr) * D + c4 * 4);
        xs[rr][c4 ^ (rr & 7)] = v;
    }
    __syncthreads();

    const int r  = tid & 63;
    const int c  = __builtin_amdgcn_readfirstlane(tid >> 6);  // wave id, forced SGPR
    const int sw = r & 7;

    // wave 0 additionally computes ||x_row||^2 (needed for loss only)
    float xnorm = 0.f;
    if (c == 0) {
        float4 a = make_float4(0.f, 0.f, 0.f, 0.f);
        for (int d4 = 0; d4 < 64; ++d4) {
            float4 xv = xs[r][d4 ^ sw];
            a.x = fmaf(xv.x, xv.x, a.x);
            a.y = fmaf(xv.y, xv.y, a.y);
            a.z = fmaf(xv.z, xv.z, a.z);
            a.w = fmaf(xv.w, xv.w, a.w);
        }
        xnorm = (a.x + a.y) + (a.z + a.w);
    }

    const float* __restrict__ enorm = ws + 1 + M;

    float bestVal = 3.4e38f;
    int   bestIdx = 0;
    // each thread: 8-embedding register block, e loads are wave-uniform (scalar)
    for (int chunk = 0; chunk < M / 32; ++chunk) {
        const int m0 = chunk * 32 + c * 8;
        float4 acc[8];
#pragma unroll
        for (int mi = 0; mi < 8; ++mi) acc[mi] = make_float4(0.f, 0.f, 0.f, 0.f);
#pragma unroll 2
        for (int d4 = 0; d4 < 64; ++d4) {
            const float4 xv = xs[r][d4 ^ sw];
#pragma unroll
            for (int mi = 0; mi < 8; ++mi) {
                const float4 ev = *reinterpret_cast<const float4*>(e + (m0 + mi) * D + d4 * 4);
                acc[mi].x = fmaf(xv.x, ev.x, acc[mi].x);
                acc[mi].y = fmaf(xv.y, ev.y, acc[mi].y);
                acc[mi].z = fmaf(xv.z, ev.z, acc[mi].z);
                acc[mi].w = fmaf(xv.w, ev.w, acc[mi].w);
            }
        }
#pragma unroll
        for (int mi = 0; mi < 8; ++mi) {
            float dot = (acc[mi].x + acc[mi].y) + (acc[mi].z + acc[mi].w);
            float val = enorm[m0 + mi] - 2.0f * dot;
            if (val < bestVal) { bestVal = val; bestIdx = m0 + mi; }  // strict <: first-min, m ascending
        }
    }
    cval[c][r] = bestVal;
    cidx[c][r] = bestIdx;
    __syncthreads();

    if (c == 0) {
        float bv = bestVal; int bi = bestIdx;
#pragma unroll
        for (int cc = 1; cc < 4; ++cc) {
            float v = cval[cc][r]; int i = cidx[cc][r];
            if (v < bv || (v == bv && i < bi)) { bv = v; bi = i; }  // tie -> lower index (np.argmin)
        }
        fidx[r] = bi;
        outIdx[row0 + r] = (float)bi;
        atomicAdd(ws + 1 + bi, 1.0f);
        float dist = bv + xnorm;   // full ||x-e||^2 via the distance formula
#pragma unroll
        for (int o = 32; o > 0; o >>= 1) dist += __shfl_down(dist, o, 64);
        if (r == 0) atomicAdd(ws, dist);
    }
    __syncthreads();

    // gather quantized = embedding[idx], coalesced
#pragma unroll
    for (int it = 0; it < 16; ++it) {
        int f  = it * 256 + tid;
        int rr = f >> 6, c4 = f & 63;
        int idx = fidx[rr];
        float4 v = *reinterpret_cast<const float4*>(e + idx * D + c4 * 4);
        *reinterpret_cast<float4*>(outQ + (row0 + rr) * D + c4 * 4) = v;
    }
}

// ---------------- kernel C: finalize loss + perplexity ----------------
__global__ void vq_final_kernel(const float* __restrict__ ws,
                                float* __restrict__ outLoss, float* __restrict__ outPpl,
                                float invN, float invND) {
    int t = threadIdx.x;  // 1024 threads, one bin each
    float p = ws[1 + t] * invN;
    float term = p * logf(p + 1e-10f);
#pragma unroll
    for (int o = 32; o > 0; o >>= 1) term += __shfl_down(term, o, 64);
    __shared__ float s[16];
    if ((t & 63) == 0) s[t >> 6] = term;
    __syncthreads();
    if (t == 0) {
        float tot = 0.f;
#pragma unroll
        for (int i = 0; i < 16; ++i) tot += s[i];
        *outPpl  = expf(-tot);
        *outLoss = 1.25f * ws[0] * invND;   // (0.25 + 1.0) * mean, LAMBDA_KL = 1
    }
}

extern "C" void kernel_launch(void* const* d_in, const int* in_sizes, int n_in,
                              void* d_out, int out_size, void* d_ws, size_t ws_size,
                              hipStream_t stream) {
    const float* x = (const float*)d_in[0];
    const float* e = (const float*)d_in[1];
    const int NX = in_sizes[0];     // N*D = 8388608
    const int N  = NX / D;          // 32768

    float* out     = (float*)d_out;
    float* outQ    = out;
    float* outLoss = out + NX;
    float* outIdx  = out + NX + 1;
    float* outPpl  = out + NX + 1 + N;
    float* ws      = (float*)d_ws;

    // zero loss accumulator + counts (captured into graph -> deterministic per replay)
    hipMemsetAsync(d_ws, 0, (1 + M) * sizeof(float), stream);
    enorm_kernel<<<M, 64, 0, stream>>>(e, ws + 1 + M);
    vq_main_kernel<<<N / ROWS, 256, 0, stream>>>(x, e, outQ, outIdx, ws);
    vq_final_kernel<<<1, 1024, 0, stream>>>(ws, outLoss, outPpl,
                                            1.0f / (float)N, 1.0f / (float)NX);
}

// Round 2
// 158.535 us; speedup vs baseline: 3.2337x; 3.2337x over previous
//
#include <hip/hip_runtime.h>

// VQEmbedding: x [N=32768, D=256] fp32, embedding [M=1024, D=256] fp32.
// Outputs (flat fp32): quantized [N*D], loss [1], indices [N] (as float), perplexity [1].
// Strategy: distances via split-fp16 MFMA (hi*hi + hi*lo + lo*hi), exact fp32 enorm,
// loss via identity sum(||x-q||^2) = ||x||_F^2 + sum(enorm[best] - 2*dot_best).

constexpr int D = 256;
constexpr int M = 1024;
constexpr int ROWS = 64;

typedef _Float16 f16;
typedef __attribute__((ext_vector_type(4))) _Float16 f16x4;
typedef __attribute__((ext_vector_type(8))) _Float16 f16x8;
typedef __attribute__((ext_vector_type(4))) float f32x4;

// ws layout (bytes):
//   [0..4)        loss accumulator (float)
//   [4..4100)     counts (1024 floats, float-idx 1..1025)
//   [4112..8208)  enorm  (1024 floats, float-idx 1028..2052)  (16B aligned)
//   [8320..532608)     eHi (1024*256 f16)
//   [532608..1056896)  eLo (1024*256 f16)
constexpr size_t WS_ENORM_F = 1028;
constexpr size_t WS_EHI_B   = 8320;
constexpr size_t WS_ELO_B   = 532608;
constexpr size_t WS_NEEDED  = 1056896;

// ---------------- prep: split e into f16 hi/lo + exact ||e||^2 ----------------
__global__ void prep_kernel(const float* __restrict__ e, float* __restrict__ ws) {
    int m = blockIdx.x, l = threadIdx.x;   // 64 threads, one float4 each
    float4 v = *reinterpret_cast<const float4*>(e + m * D + l * 4);
    f16 h0 = (f16)v.x, h1 = (f16)v.y, h2 = (f16)v.z, h3 = (f16)v.w;
    f16x4 hv = {h0, h1, h2, h3};
    f16x4 lv = {(f16)(v.x - (float)h0), (f16)(v.y - (float)h1),
                (f16)(v.z - (float)h2), (f16)(v.w - (float)h3)};
    f16* eHi = reinterpret_cast<f16*>((char*)ws + WS_EHI_B);
    f16* eLo = reinterpret_cast<f16*>((char*)ws + WS_ELO_B);
    *reinterpret_cast<f16x4*>(eHi + m * D + l * 4) = hv;
    *reinterpret_cast<f16x4*>(eLo + m * D + l * 4) = lv;
    float s = fmaf(v.x, v.x, fmaf(v.y, v.y, fmaf(v.z, v.z, v.w * v.w)));
#pragma unroll
    for (int o = 32; o > 0; o >>= 1) s += __shfl_down(s, o, 64);
    if (l == 0) ws[WS_ENORM_F + m] = s;
}

// ---------------- main MFMA kernel ----------------
__global__ __launch_bounds__(256, 2) void vq_mfma_kernel(
    const float* __restrict__ x, const float* __restrict__ e,
    float* __restrict__ outQ, float* __restrict__ outIdx, float* __restrict__ ws)
{
    __shared__ ushort xHi[ROWS * D];   // 32 KB, XOR-swizzled by ((row&7)<<4) on byte addr
    __shared__ ushort xLo[ROWS * D];   // 32 KB
    __shared__ float  enorm_s[M];      // 4 KB
    __shared__ float  wval[4][ROWS];
    __shared__ int    widx[4][ROWS];
    __shared__ int    fidx[ROWS];

    const int tid  = threadIdx.x;
    const int row0 = blockIdx.x * ROWS;

    // enorm -> LDS (1024 floats)
    {
        float4 v = *reinterpret_cast<const float4*>(ws + WS_ENORM_F + tid * 4);
        *reinterpret_cast<float4*>(&enorm_s[tid * 4]) = v;
    }

    // stage x tile: fp32 -> f16 hi/lo into swizzled LDS; accumulate ||x||_F^2 exactly
    float sxx = 0.f;
#pragma unroll
    for (int it = 0; it < 16; ++it) {
        int f  = it * 256 + tid;
        int rr = f >> 6, c4 = f & 63;   // per-wave rr uniform -> contiguous 512B row writes
        float4 v = *reinterpret_cast<const float4*>(x + (row0 + rr) * D + c4 * 4);
        sxx += fmaf(v.x, v.x, fmaf(v.y, v.y, fmaf(v.z, v.z, v.w * v.w)));
        f16 h0 = (f16)v.x, h1 = (f16)v.y, h2 = (f16)v.z, h3 = (f16)v.w;
        f16x4 hv = {h0, h1, h2, h3};
        f16x4 lv = {(f16)(v.x - (float)h0), (f16)(v.y - (float)h1),
                    (f16)(v.z - (float)h2), (f16)(v.w - (float)h3)};
        int byte = (rr * 512 + c4 * 8) ^ ((rr & 7) << 4);
        *reinterpret_cast<f16x4*>((char*)xHi + byte) = hv;
        *reinterpret_cast<f16x4*>((char*)xLo + byte) = lv;
    }
#pragma unroll
    for (int o = 32; o > 0; o >>= 1) sxx += __shfl_down(sxx, o, 64);
    if ((tid & 63) == 0) atomicAdd(ws, sxx);
    __syncthreads();

    const int l  = tid & 63;
    const int w  = __builtin_amdgcn_readfirstlane(tid >> 6);  // wave id (SGPR)
    const int lr = l & 15;      // A-row / B-col within frag
    const int q  = l >> 4;      // k-group
    const int aswz = (lr & 7) << 4;
    const f16* eHi = reinterpret_cast<const f16*>((const char*)ws + WS_EHI_B);
    const f16* eLo = reinterpret_cast<const f16*>((const char*)ws + WS_ELO_B);

    float bestV[16];
    int   bestI[16];
#pragma unroll
    for (int s = 0; s < 16; ++s) { bestV[s] = 3.4e38f; bestI[s] = 0; }

    for (int chunk = 0; chunk < 4; ++chunk) {
        const int m0 = w * 256 + chunk * 64;   // wave w owns cols [w*256, w*256+256)
        f32x4 acc[4][4];
#pragma unroll
        for (int rf = 0; rf < 4; ++rf)
#pragma unroll
            for (int cf = 0; cf < 4; ++cf) acc[rf][cf] = (f32x4){0.f, 0.f, 0.f, 0.f};

#pragma unroll
        for (int kk = 0; kk < 8; ++kk) {
            f16x8 ah[4], al[4], bh[4], bl[4];
#pragma unroll
            for (int rf = 0; rf < 4; ++rf) {
                int byte = (((rf * 16 + lr) * 512) + kk * 64 + q * 16) ^ aswz;
                ah[rf] = *reinterpret_cast<const f16x8*>((const char*)xHi + byte);
                al[rf] = *reinterpret_cast<const f16x8*>((const char*)xLo + byte);
            }
#pragma unroll
            for (int cf = 0; cf < 4; ++cf) {
                int eidx = (m0 + cf * 16 + lr) * D + kk * 32 + q * 8;
                bh[cf] = *reinterpret_cast<const f16x8*>(eHi + eidx);
                bl[cf] = *reinterpret_cast<const f16x8*>(eLo + eidx);
            }
#pragma unroll
            for (int rf = 0; rf < 4; ++rf)
#pragma unroll
                for (int cf = 0; cf < 4; ++cf) {
                    acc[rf][cf] = __builtin_amdgcn_mfma_f32_16x16x32_f16(ah[rf], bh[cf], acc[rf][cf], 0, 0, 0);
                    acc[rf][cf] = __builtin_amdgcn_mfma_f32_16x16x32_f16(ah[rf], bl[cf], acc[rf][cf], 0, 0, 0);
                    acc[rf][cf] = __builtin_amdgcn_mfma_f32_16x16x32_f16(al[rf], bh[cf], acc[rf][cf], 0, 0, 0);
                }
        }
        // fold distances into running per-lane argmin (m ascending -> strict < = first min)
#pragma unroll
        for (int cf = 0; cf < 4; ++cf) {
            float en = enorm_s[m0 + cf * 16 + lr];
            int   mi = m0 + cf * 16 + lr;
#pragma unroll
            for (int rf = 0; rf < 4; ++rf)
#pragma unroll
                for (int i = 0; i < 4; ++i) {
                    float dv = fmaf(-2.f, acc[rf][cf][i], en);
                    int s = rf * 4 + i;
                    if (dv < bestV[s]) { bestV[s] = dv; bestI[s] = mi; }
                }
        }
    }

    // reduce across the 16 lanes sharing each row (xor within l&15), tie -> lower idx
#pragma unroll
    for (int s = 0; s < 16; ++s) {
        float v = bestV[s]; int ix = bestI[s];
#pragma unroll
        for (int mk = 1; mk < 16; mk <<= 1) {
            float ov = __shfl_xor(v, mk, 64);
            int   oi = __shfl_xor(ix, mk, 64);
            if (ov < v || (ov == v && oi < ix)) { v = ov; ix = oi; }
        }
        bestV[s] = v; bestI[s] = ix;
    }
    if (lr == 0) {
#pragma unroll
        for (int s = 0; s < 16; ++s) {
            int row = (s >> 2) * 16 + q * 4 + (s & 3);
            wval[w][row] = bestV[s];
            widx[w][row] = bestI[s];
        }
    }
    __syncthreads();

    // wave 0: combine the 4 waves' column ranges, emit idx/counts/loss partials
    if (tid < 64) {
        int r = tid;
        float bv = wval[0][r]; int bi = widx[0][r];
#pragma unroll
        for (int ww = 1; ww < 4; ++ww) {
            float v = wval[ww][r]; int i2 = widx[ww][r];
            if (v < bv || (v == bv && i2 < bi)) { bv = v; bi = i2; }
        }
        fidx[r] = bi;
        outIdx[row0 + r] = (float)bi;
        atomicAdd(ws + 1 + bi, 1.0f);
        float dsum = bv;
#pragma unroll
        for (int o = 32; o > 0; o >>= 1) dsum += __shfl_down(dsum, o, 64);
        if (r == 0) atomicAdd(ws, dsum);
    }
    __syncthreads();

    // gather quantized = embedding[idx] (exact fp32), coalesced
#pragma unroll
    for (int it = 0; it < 16; ++it) {
        int f  = it * 256 + tid;
        int rr = f >> 6, c4 = f & 63;
        int idx = fidx[rr];
        float4 v = *reinterpret_cast<const float4*>(e + idx * D + c4 * 4);
        *reinterpret_cast<float4*>(outQ + (row0 + rr) * D + c4 * 4) = v;
    }
}

// ---------------- fallback fp32 kernels (used only if ws too small) ----------------
__global__ void enorm_kernel(const float* __restrict__ e, float* __restrict__ enorm) {
    int m = blockIdx.x;
    int l = threadIdx.x;
    const float4 v = *reinterpret_cast<const float4*>(e + m * D + l * 4);
    float s = fmaf(v.x, v.x, fmaf(v.y, v.y, fmaf(v.z, v.z, v.w * v.w)));
#pragma unroll
    for (int o = 32; o > 0; o >>= 1) s += __shfl_down(s, o, 64);
    if (l == 0) enorm[m] = s;
}

__global__ __launch_bounds__(256, 2) void vq_main_kernel(
    const float* __restrict__ x, const float* __restrict__ e,
    float* __restrict__ outQ, float* __restrict__ outIdx,
    float* __restrict__ ws) {
    __shared__ float4 xs[ROWS][64];
    __shared__ float cval[4][ROWS];
    __shared__ int   cidx[4][ROWS];
    __shared__ int   fidx[ROWS];

    const int tid  = threadIdx.x;
    const int row0 = blockIdx.x * ROWS;

#pragma unroll
    for (int it = 0; it < 16; ++it) {
        int f  = it * 256 + tid;
        int rr = f >> 6, c4 = f & 63;
        float4 v = *reinterpret_cast<const float4*>(x + (row0 + rr) * D + c4 * 4);
        xs[rr][c4 ^ (rr & 7)] = v;
    }
    __syncthreads();

    const int r  = tid & 63;
    const int c  = __builtin_amdgcn_readfirstlane(tid >> 6);
    const int sw = r & 7;

    float xnorm = 0.f;
    if (c == 0) {
        float4 a = make_float4(0.f, 0.f, 0.f, 0.f);
        for (int d4 = 0; d4 < 64; ++d4) {
            float4 xv = xs[r][d4 ^ sw];
            a.x = fmaf(xv.x, xv.x, a.x);
            a.y = fmaf(xv.y, xv.y, a.y);
            a.z = fmaf(xv.z, xv.z, a.z);
            a.w = fmaf(xv.w, xv.w, a.w);
        }
        xnorm = (a.x + a.y) + (a.z + a.w);
    }

    const float* __restrict__ enorm = ws + WS_ENORM_F;

    float bestVal = 3.4e38f;
    int   bestIdx = 0;
    for (int chunk = 0; chunk < M / 32; ++chunk) {
        const int m0 = chunk * 32 + c * 8;
        float4 acc[8];
#pragma unroll
        for (int mi = 0; mi < 8; ++mi) acc[mi] = make_float4(0.f, 0.f, 0.f, 0.f);
#pragma unroll 2
        for (int d4 = 0; d4 < 64; ++d4) {
            const float4 xv = xs[r][d4 ^ sw];
#pragma unroll
            for (int mi = 0; mi < 8; ++mi) {
                const float4 ev = *reinterpret_cast<const float4*>(e + (m0 + mi) * D + d4 * 4);
                acc[mi].x = fmaf(xv.x, ev.x, acc[mi].x);
                acc[mi].y = fmaf(xv.y, ev.y, acc[mi].y);
                acc[mi].z = fmaf(xv.z, ev.z, acc[mi].z);
                acc[mi].w = fmaf(xv.w, ev.w, acc[mi].w);
            }
        }
#pragma unroll
        for (int mi = 0; mi < 8; ++mi) {
            float dot = (acc[mi].x + acc[mi].y) + (acc[mi].z + acc[mi].w);
            float val = enorm[m0 + mi] - 2.0f * dot;
            if (val < bestVal) { bestVal = val; bestIdx = m0 + mi; }
        }
    }
    cval[c][r] = bestVal;
    cidx[c][r] = bestIdx;
    __syncthreads();

    if (c == 0) {
        float bv = bestVal; int bi = bestIdx;
#pragma unroll
        for (int cc = 1; cc < 4; ++cc) {
            float v = cval[cc][r]; int i = cidx[cc][r];
            if (v < bv || (v == bv && i < bi)) { bv = v; bi = i; }
        }
        fidx[r] = bi;
        outIdx[row0 + r] = (float)bi;
        atomicAdd(ws + 1 + bi, 1.0f);
        float dist = bv + xnorm;
#pragma unroll
        for (int o = 32; o > 0; o >>= 1) dist += __shfl_down(dist, o, 64);
        if (r == 0) atomicAdd(ws, dist);
    }
    __syncthreads();

#pragma unroll
    for (int it = 0; it < 16; ++it) {
        int f  = it * 256 + tid;
        int rr = f >> 6, c4 = f & 63;
        int idx = fidx[rr];
        float4 v = *reinterpret_cast<const float4*>(e + idx * D + c4 * 4);
        *reinterpret_cast<float4*>(outQ + (row0 + rr) * D + c4 * 4) = v;
    }
}

// ---------------- finalize: loss + perplexity ----------------
__global__ void vq_final_kernel(const float* __restrict__ ws,
                                float* __restrict__ outLoss, float* __restrict__ outPpl,
                                float invN, float invND) {
    int t = threadIdx.x;  // 1024 threads, one bin each
    float p = ws[1 + t] * invN;
    float term = p * logf(p + 1e-10f);
#pragma unroll
    for (int o = 32; o > 0; o >>= 1) term += __shfl_down(term, o, 64);
    __shared__ float s[16];
    if ((t & 63) == 0) s[t >> 6] = term;
    __syncthreads();
    if (t == 0) {
        float tot = 0.f;
#pragma unroll
        for (int i = 0; i < 16; ++i) tot += s[i];
        *outPpl  = expf(-tot);
        *outLoss = 1.25f * ws[0] * invND;
    }
}

extern "C" void kernel_launch(void* const* d_in, const int* in_sizes, int n_in,
                              void* d_out, int out_size, void* d_ws, size_t ws_size,
                              hipStream_t stream) {
    const float* x = (const float*)d_in[0];
    const float* e = (const float*)d_in[1];
    const int NX = in_sizes[0];     // N*D = 8388608
    const int N  = NX / D;          // 32768

    float* out     = (float*)d_out;
    float* outQ    = out;
    float* outLoss = out + NX;
    float* outIdx  = out + NX + 1;
    float* outPpl  = out + NX + 1 + N;
    float* ws      = (float*)d_ws;

    hipMemsetAsync(d_ws, 0, (1 + M) * sizeof(float), stream);
    if (ws_size >= WS_NEEDED) {
        prep_kernel<<<M, 64, 0, stream>>>(e, ws);
        vq_mfma_kernel<<<N / ROWS, 256, 0, stream>>>(x, e, outQ, outIdx, ws);
    } else {
        enorm_kernel<<<M, 64, 0, stream>>>(e, ws + WS_ENORM_F);
        vq_main_kernel<<<N / ROWS, 256, 0, stream>>>(x, e, outQ, outIdx, ws);
    }
    vq_final_kernel<<<1, 1024, 0, stream>>>(ws, outLoss, outPpl,
                                            1.0f / (float)N, 1.0f / (float)NX);
}